// Round 8
// baseline (10652.694 us; speedup 1.0000x reference)
//
#include <hip/hip_runtime.h>

// TrainerRNN: 10-layer GRU (T=2048, IN=384, H=768) + linear head (384).
// ROUND 13: XCD-local layers, two 5-layer phases.
// Evidence: R10-R12 invariant ~3.3us/row across all detect/traffic variants
// => row period is the agent(sc1)/MALL RTT (~1us) itself. Shorten the wire:
//  - one layer = 24 blocks = one XCD; intra-layer recurrence via sc0
//    (L1-bypass, L2-coherent) inline-asm loads/stores: ~5x shorter RTT.
//  - 10 layers > 8 XCDs => TWO sequential phases of 5 layers (pipeline time
//    doesn't depend on layer count). Phase1: x -> h4 (fp16; numerically
//    free, every layer input already passes through fp16 staging).
//    Phase2: h4 -> h9 (fp32) -> fc_head.
//  - placement: blocks read XCC_ID (hwreg 20, learn_hip m09), claim roles
//    from per-XCD rosters (exactly-once atomicExch; sleep-then-steal
//    fallback => all roles always claimed, no deadlock). A per-layer
//    handshake (rolexcd table) verifies all 24 blocks share one XCD; else
//    that layer publishes sc1 (correct, R12-speed). Consumers ALWAYS
//    alternate near(sc0)/far(sc1) samples => correctness never depends on
//    placement; mis-placement costs speed only.
//  - ring_loc (sc0 domain, own-layer recurrence) and ring_dwn (sc1 domain,
//    inter-layer shadow, has a full row of slack) are SEPARATE buffers =>
//    no mixed sc0/sc1 same-address writeback hazard; each word has one
//    producer and one domain.
// Numerics identical to R12: fp32 w_hh regs, fp16 w_ih + dot2, tag-in-
// mantissa packing (<=2e-6), h4 handoff = the same fp16 staging quantum.

#define T_SEQ 2048
#define H_DIM 768
#define IN0   384
#define G3    2304
#define NLL   5                       // layers per phase
#define BPL   24                      // blocks per layer
#define NROLE (NLL * BPL)             // 120 worker roles per phase
#define NBLK  256                     // grid = CU count; unclaimed blocks exit
#define UPB   32
#define NTHR  512                     // 8 waves x 4 units x 16 lanes
#define NOUT  384
#define CTR_STRIDE 32
#define RING  16
#define WPR   384                     // packed words per row
#define WIH_STRIDE 776
#define HCS_STRIDE 52
#define HSD_STRIDE 56
#define HSD0_STRIDE 32

typedef _Float16 half2_t __attribute__((ext_vector_type(2)));
typedef _Float16 half8_t __attribute__((ext_vector_type(8)));
typedef unsigned long long u64;

__device__ __forceinline__ float sigm(float x) { return 1.0f / (1.0f + __expf(-x)); }

// far = agent scope (sc0 sc1, MALL-coherent) -- compiler-scheduled
__device__ __forceinline__ u64 ld64_far(const u64* p) {
    return __hip_atomic_load(p, __ATOMIC_RELAXED, __HIP_MEMORY_SCOPE_AGENT);
}
__device__ __forceinline__ void st64_far(u64* p, u64 v) {
    __hip_atomic_store(p, v, __ATOMIC_RELAXED, __HIP_MEMORY_SCOPE_AGENT);
}
// near = sc0 only (L1-bypass, L2-resident): XCD-local fast path
__device__ __forceinline__ u64 ld64_near(const u64* p) {
    u64 v;
    asm volatile("global_load_dwordx2 %0, %1, off sc0\n\ts_waitcnt vmcnt(0)"
                 : "=v"(v) : "v"(p) : "memory");
    return v;
}
__device__ __forceinline__ void st64_near(u64* p, u64 v) {
    asm volatile("global_store_dwordx2 %0, %1, off sc0" :: "v"(p), "v"(v) : "memory");
}
__device__ __forceinline__ unsigned ldctr(const unsigned* p) {
    return __hip_atomic_load(p, __ATOMIC_RELAXED, __HIP_MEMORY_SCOPE_AGENT);
}
__device__ __forceinline__ int tagok(u64 v, unsigned tg) {
    return (((unsigned)v & 31u) == tg) & ((((unsigned)(v >> 32)) & 31u) == tg);
}

__device__ __forceinline__ float dot8(half8_t h, half8_t w, float acc) {
    union U { half8_t v; unsigned u[4]; };
    U H; H.v = h; U W; W.v = w;
#pragma unroll
    for (int j = 0; j < 4; ++j) {
#if __has_builtin(__builtin_amdgcn_fdot2)
        acc = __builtin_amdgcn_fdot2(__builtin_bit_cast(half2_t, H.u[j]),
                                     __builtin_bit_cast(half2_t, W.u[j]), acc, false);
#else
        half2_t a = __builtin_bit_cast(half2_t, H.u[j]);
        half2_t b = __builtin_bit_cast(half2_t, W.u[j]);
        asm volatile("v_dot2_f32_f16 %0, %1, %2, %0" : "+v"(acc) : "v"(a), "v"(b));
#endif
    }
    return acc;
}

extern "C" __global__ __launch_bounds__(NTHR, 1) void gru_phase(
    const void* fin, int fin_is16, int layer_base,
    const float* __restrict__ wih0, const float* __restrict__ whh0,
    const float* __restrict__ bih0, const float* __restrict__ bhh0,
    const float* __restrict__ wihS, const float* __restrict__ whhS,
    const float* __restrict__ bihS, const float* __restrict__ bhhS,
    u64* __restrict__ ring_loc, u64* __restrict__ ring_dwn,
    unsigned int* __restrict__ ctr, int* __restrict__ taken,
    int* __restrict__ rolexcd,
    float* __restrict__ hout32, _Float16* __restrict__ hout16)
{
    __shared__ __align__(16) _Float16 wih16[96 * WIH_STRIDE];       // 148,992 B
    __shared__ __align__(16) float    hcs[2][16 * HCS_STRIDE];      //   6,656 B
    __shared__ __align__(16) _Float16 hsd16[2][16 * HSD_STRIDE];    //   3,584 B
    __shared__ int s_role, s_local;

    const int tid  = threadIdx.x;
    const int lane = tid & 63;
    const int wv   = tid >> 6;
    const int p    = lane & 15;
    const int ulocal = wv * 4 + (lane >> 4);

    // ---- role claim + locality handshake (tid 0) ----
    if (tid == 0) {
        int xcd = 0;
        asm volatile("s_getreg_b32 %0, hwreg(20, 0, 32)" : "=s"(xcd)); // XCC_ID (m09); wrong value => slower, never wrong
        xcd &= 7;
        int role = -1;
        if (xcd < NLL) {
            const int b0 = xcd * BPL;
            for (int r = b0; r < b0 + BPL; ++r)
                if (atomicExch(&taken[r], 1) == 0) { role = r; break; }
        }
        if (role < 0) {
            for (int w = 0; w < 300; ++w) __builtin_amdgcn_s_sleep(8);  // ~60us: let locals claim
            for (int r = 0; r < NROLE && role < 0; ++r)
                if (atomicExch(&taken[r], 1) == 0) role = r;
        }
        int loc = 0;
        if (role >= 0) {
            __hip_atomic_store(&rolexcd[role], xcd + 1,
                               __ATOMIC_RELEASE, __HIP_MEMORY_SCOPE_AGENT);
            const int lb = (role / BPL) * BPL;
            loc = 1;
            for (int r = lb; r < lb + BPL; ++r) {
                int v;
                while ((v = __hip_atomic_load(&rolexcd[r], __ATOMIC_ACQUIRE,
                                              __HIP_MEMORY_SCOPE_AGENT)) == 0)
                    __builtin_amdgcn_s_sleep(2);
                if (v != xcd + 1) loc = 0;
            }
        }
        s_role = role; s_local = loc;
    }
    __syncthreads();
    const int role = s_role;
    if (role < 0) return;                      // surplus block
    const bool uselocal = (s_local != 0);
    const int layer = role / BPL;              // phase-local 0..4
    const int sub   = role % BPL;
    const int uglob = sub * UPB + ulocal;
    const int lg    = layer_base + layer;      // global layer 0..9
    const int Din   = lg ? H_DIM : IN0;
    const bool din384 = (Din == IN0);

    const float* wihL = lg ? wihS + (size_t)(lg - 1) * G3 * H_DIM : wih0;
    const float* whhL = lg ? whhS + (size_t)(lg - 1) * G3 * H_DIM : whh0;
    const float* bihL = lg ? bihS + (size_t)(lg - 1) * G3 : bih0;
    const float* bhhL = lg ? bhhS + (size_t)(lg - 1) * G3 : bhh0;

    // ---- w_hh -> registers (3 gates x 12 float4 per thread) ----
    float4 wr[3][12];
#pragma unroll
    for (int gate = 0; gate < 3; ++gate) {
        const float4* src = (const float4*)(whhL + (size_t)(uglob + gate * H_DIM) * H_DIM + 48 * p);
#pragma unroll
        for (int i = 0; i < 12; ++i) wr[gate][i] = src[i];
    }
    const float bhr  = bhhL[uglob], bhz = bhhL[uglob + H_DIM], bhn  = bhhL[uglob + 2 * H_DIM];
    const float bir  = bihL[uglob], biz = bihL[uglob + H_DIM], bin_ = bihL[uglob + 2 * H_DIM];

    // ---- w_ih -> LDS fp16 ----
    for (int rr = 0; rr < 12; ++rr) {
        const int r = wv * 12 + rr;
        const int u = r / 3, G = r % 3;
        const float* src = wihL + (size_t)(sub * UPB + u + G * H_DIM) * Din;
        _Float16* dst = wih16 + r * WIH_STRIDE;
        for (int k = lane; k < Din; k += 64) dst[k] = (_Float16)src[k];
    }
    __syncthreads();

    auto stage_hsd = [&](int b, int w, u64 v) {
        const int s = w / 24, idx = (2 * w) % 48;
        const _Float16 a = (_Float16)__uint_as_float((unsigned)v & ~31u);
        const _Float16 c = (_Float16)__uint_as_float((unsigned)(v >> 32) & ~31u);
        const unsigned pk = (unsigned)__builtin_bit_cast(unsigned short, a)
                          | ((unsigned)__builtin_bit_cast(unsigned short, c) << 16);
        *(unsigned*)&hsd16[b][s * HSD_STRIDE + idx] = pk;
    };
    auto stage_fin = [&](int b, int row) {       // untagged input rows
        if (din384) {
            if (tid < IN0)
                hsd16[b][(tid / 24) * HSD0_STRIDE + tid % 24] = fin_is16
                    ? ((const _Float16*)fin)[(size_t)row * IN0 + tid]
                    : (_Float16)((const float*)fin)[(size_t)row * IN0 + tid];
        } else {
            const _Float16* f16 = (const _Float16*)fin;
            for (int vi = tid; vi < H_DIM; vi += NTHR)
                hsd16[b][(vi / 48) * HSD_STRIDE + vi % 48] = f16[(size_t)row * H_DIM + vi];
        }
    };

    float gi_r = 0.f, gi_z = 0.f, gi_n = 0.f;
    auto ih_gemv = [&](int b) {
        float sr = 0.f, sz = 0.f, sn = 0.f;
        if (!din384) {
            const half8_t* h8 = (const half8_t*)(&hsd16[b][p * HSD_STRIDE]);
            const half8_t* w0 = (const half8_t*)(wih16 + (ulocal * 3 + 0) * WIH_STRIDE + 48 * p);
            const half8_t* w1 = (const half8_t*)(wih16 + (ulocal * 3 + 1) * WIH_STRIDE + 48 * p);
            const half8_t* wn = (const half8_t*)(wih16 + (ulocal * 3 + 2) * WIH_STRIDE + 48 * p);
#pragma unroll
            for (int i = 0; i < 6; ++i) {
                const half8_t hv = h8[i];
                sr = dot8(hv, w0[i], sr); sz = dot8(hv, w1[i], sz); sn = dot8(hv, wn[i], sn);
            }
        } else {
            const half8_t* h8 = (const half8_t*)(&hsd16[b][p * HSD0_STRIDE]);
            const half8_t* w0 = (const half8_t*)(wih16 + (ulocal * 3 + 0) * WIH_STRIDE + 24 * p);
            const half8_t* w1 = (const half8_t*)(wih16 + (ulocal * 3 + 1) * WIH_STRIDE + 24 * p);
            const half8_t* wn = (const half8_t*)(wih16 + (ulocal * 3 + 2) * WIH_STRIDE + 24 * p);
#pragma unroll
            for (int i = 0; i < 3; ++i) {
                const half8_t hv = h8[i];
                sr = dot8(hv, w0[i], sr); sz = dot8(hv, w1[i], sz); sn = dot8(hv, wn[i], sn);
            }
        }
#pragma unroll
        for (int off = 1; off <= 8; off <<= 1) {
            sr += __shfl_xor(sr, off, 64);
            sz += __shfl_xor(sz, off, 64);
            sn += __shfl_xor(sn, off, 64);
        }
        gi_r = sr + bir; gi_z = sz + biz; gi_n = sn + bin_;
    };

    // ---- prologue gi(0): layer 0 from fin; else far-spin ring_dwn slot 0 ----
    if (layer) {
        if (tid < WPR) {
            const u64* sp = ring_dwn + (size_t)(layer - 1) * RING * WPR + tid;
            u64 v = 0;
            while (!tagok(v, 1u)) v = ld64_far(sp);
            stage_hsd(1, tid, v);
        }
    } else {
        stage_fin(1, 0);
    }
    __syncthreads();
    ih_gemv(1);

    u64 sa0 = 0;                         // shadow early sample
    if (layer && tid < WPR)
        sa0 = ld64_far(ring_dwn + ((size_t)(layer - 1) * RING + 1) * WPR + tid);

    unsigned bp = 0;

    for (int t = 0; t < T_SEQ; ++t) {
        const int b = t & 1;
        const bool have_s = (t + 1) < T_SEQ;

        // ---- back-pressure (protects ring_dwn slot reuse; amortized) ----
        if (layer != NLL - 1 && t >= 16 && (t & 3) == 0) {
            const unsigned tgt = 24u * (unsigned)((t - 12) >> 2);
            while (bp < tgt) {
                __builtin_amdgcn_s_sleep(2);
                bp = ldctr(&ctr[(layer + 1) * CTR_STRIDE]);
            }
        }

        // ---- 1: own h(t-1) detect on ring_loc: near first, alternate far ----
        if (t > 0 && tid < WPR) {
            const u64* hr = ring_loc + ((size_t)layer * RING + ((t - 1) & (RING - 1))) * WPR + tid;
            const unsigned tg = (unsigned)t & 31u;
            u64 v = ld64_near(hr);
            int k = 0;
            while (!tagok(v, tg)) v = (++k & 1) ? ld64_far(hr) : ld64_near(hr);
            const int s = tid / 24, idx = (2 * tid) % 48;
            float2 hv;
            hv.x = __uint_as_float((unsigned)v & ~31u);
            hv.y = __uint_as_float((unsigned)(v >> 32) & ~31u);
            *(float2*)&hcs[b][s * HCS_STRIDE + idx] = hv;
        }

        // ---- 2: shadow (l-1, t+1) from ring_dwn (tag t+2), or fin row t+1 ----
        if (have_s) {
            if (layer) {
                if (tid < WPR) {
                    const u64* sp = ring_dwn + ((size_t)(layer - 1) * RING + ((t + 1) & (RING - 1))) * WPR + tid;
                    const unsigned tg2 = (unsigned)(t + 2) & 31u;
                    u64 v = sa0;
                    while (!tagok(v, tg2)) v = ld64_far(sp);
                    stage_hsd(b, tid, v);
                }
            } else {
                stage_fin(b, t + 1);
            }
        }

        // ---- 3: the row's single barrier ----
        __syncthreads();

        // ---- 4: hh GEMV (fp32 reg weights) + butterfly + gates + stores ----
        float ar = 0.f, az = 0.f, an = 0.f;
        if (t > 0) {
            const float4* hs = (const float4*)(&hcs[b][p * HCS_STRIDE]);
#pragma unroll
            for (int i = 0; i < 12; ++i) {
                const float4 h4 = hs[i];
                ar += h4.x * wr[0][i].x + h4.y * wr[0][i].y + h4.z * wr[0][i].z + h4.w * wr[0][i].w;
                az += h4.x * wr[1][i].x + h4.y * wr[1][i].y + h4.z * wr[1][i].z + h4.w * wr[1][i].w;
                an += h4.x * wr[2][i].x + h4.y * wr[2][i].y + h4.z * wr[2][i].z + h4.w * wr[2][i].w;
            }
        }
#pragma unroll
        for (int off = 1; off <= 8; off <<= 1) {
            ar += __shfl_xor(ar, off, 64);
            az += __shfl_xor(az, off, 64);
            an += __shfl_xor(an, off, 64);
        }
        {
            const float hp = (t > 0) ? hcs[b][(uglob / 48) * HCS_STRIDE + uglob % 48] : 0.f;
            const float r = sigm(ar + bhr + gi_r);
            const float z = sigm(az + bhz + gi_z);
            const float n = tanhf(gi_n + r * (an + bhn));
            const float hnew = (1.f - z) * n + z * hp;
            const float hpart = __shfl_xor(hnew, 16, 64);
            if (p == 0 && (lane & 16) == 0) {
                const unsigned tg1 = (unsigned)(t + 1) & 31u;
                const unsigned lo = (__float_as_uint(hnew)  & ~31u) | tg1;
                const unsigned hi = (__float_as_uint(hpart) & ~31u) | tg1;
                const u64 w = ((u64)hi << 32) | (u64)lo;
                const size_t base = ((size_t)layer * RING + (t & (RING - 1))) * WPR + (uglob >> 1);
                if (uselocal) st64_near(&ring_loc[base], w);
                else          st64_far (&ring_loc[base], w);
                if (layer < NLL - 1) st64_far(&ring_dwn[base], w);
            }
            if (layer == NLL - 1 && p == 0) {
                if (hout16) hout16[(size_t)t * H_DIM + uglob] = (_Float16)hnew;
                else        hout32[(size_t)t * H_DIM + uglob] = hnew;
            }
        }

        // ---- 5: issue next shadow sample (flies under ih_gemv) ----
        if (layer && tid < WPR && (t + 2) < T_SEQ)
            sa0 = ld64_far(ring_dwn + ((size_t)(layer - 1) * RING + ((t + 2) & (RING - 1))) * WPR + tid);

        // ---- 6: ih GEMV -> gi(t+1) ----
        if (have_s) ih_gemv(b);

        // ---- 7: progress bump + back-pressure prefetch ----
        if ((t & 3) == 3) {
            if (tid == 0 && layer)
                __hip_atomic_fetch_add(&ctr[layer * CTR_STRIDE], 1u,
                                       __ATOMIC_RELAXED, __HIP_MEMORY_SCOPE_AGENT);
            if (layer != NLL - 1)
                bp = ldctr(&ctr[(layer + 1) * CTR_STRIDE]);
        }
    }
}

extern "C" __global__ __launch_bounds__(NOUT, 1) void fc_head(
    const float* __restrict__ h,
    const float* __restrict__ fw,
    const float* __restrict__ fb,
    float* __restrict__ out)
{
    __shared__ float hs[H_DIM];
    const int t = blockIdx.x;
    const float* hr = h + (size_t)t * H_DIM;
    for (int k = threadIdx.x; k < H_DIM; k += NOUT) hs[k] = hr[k];
    __syncthreads();

    const int o = threadIdx.x;
    const float4* wr4 = (const float4*)(fw + (size_t)o * H_DIM);
    const float4* hs4 = (const float4*)hs;
    float acc = fb[o];
#pragma unroll 8
    for (int k = 0; k < H_DIM / 4; ++k) {
        const float4 w = wr4[k], hv = hs4[k];
        acc += w.x * hv.x + w.y * hv.y + w.z * hv.z + w.w * hv.w;
    }
    out[(size_t)t * NOUT + o] = acc;
}

extern "C" void kernel_launch(void* const* d_in, const int* in_sizes, int n_in,
                              void* d_out, int out_size, void* d_ws, size_t ws_size,
                              hipStream_t stream)
{
    const float* x    = (const float*)d_in[0];
    const float* wih0 = (const float*)d_in[1];
    const float* whh0 = (const float*)d_in[2];
    const float* bih0 = (const float*)d_in[3];
    const float* bhh0 = (const float*)d_in[4];
    const float* wihS = (const float*)d_in[5];
    const float* whhS = (const float*)d_in[6];
    const float* bihS = (const float*)d_in[7];
    const float* bhhS = (const float*)d_in[8];
    const float* fcw  = (const float*)d_in[9];
    const float* fcb  = (const float*)d_in[10];

    char* ws = (char*)d_ws;
    const size_t RSZ = (size_t)NLL * RING * WPR * 8;       // 245,760 B per ring
    int*      taken0   = (int*)(ws + 0);
    int*      taken1   = (int*)(ws + 1024);
    int*      rolexcd0 = (int*)(ws + 2048);
    int*      rolexcd1 = (int*)(ws + 3072);
    unsigned* ctr0     = (unsigned*)(ws + 8192);
    unsigned* ctr1     = (unsigned*)(ws + 16384);
    u64* ring_loc0 = (u64*)(ws + 65536);
    u64* ring_dwn0 = (u64*)(ws + 65536 + RSZ);
    u64* ring_loc1 = (u64*)(ws + 65536 + 2 * RSZ);
    u64* ring_dwn1 = (u64*)(ws + 65536 + 3 * RSZ);
    _Float16* h4 = (_Float16*)(ws + 1048576);              // 2048x768 fp16 = 3,145,728
    float*    h9 = (float*)(ws + 4194304);                 // 2048x768 fp32 = 6,291,456

    hipMemsetAsync(ws, 0, 65536, stream);                  // claims + counters
    hipMemsetAsync(ws + 65536, 0, 4 * RSZ, stream);        // ring tags = 0 (invalid)

    // Phase 1: layers 0-4, x (fp32, 384) -> h4 (fp16)
    hipLaunchKernelGGL(gru_phase, dim3(NBLK), dim3(NTHR), 0, stream,
                       (const void*)x, 0, 0,
                       wih0, whh0, bih0, bhh0, wihS, whhS, bihS, bhhS,
                       ring_loc0, ring_dwn0, ctr0, taken0, rolexcd0,
                       (float*)nullptr, h4);

    // Phase 2: layers 5-9, h4 (fp16, 768) -> h9 (fp32)
    hipLaunchKernelGGL(gru_phase, dim3(NBLK), dim3(NTHR), 0, stream,
                       (const void*)h4, 1, NLL,
                       wih0, whh0, bih0, bhh0, wihS, whhS, bihS, bhhS,
                       ring_loc1, ring_dwn1, ctr1, taken1, rolexcd1,
                       h9, (_Float16*)nullptr);

    hipLaunchKernelGGL(fc_head, dim3(T_SEQ), dim3(NOUT), 0, stream,
                       h9, fcw, fcb, (float*)d_out);
}